// Round 1
// baseline (521.279 us; speedup 1.0000x reference)
//
#include <hip/hip_runtime.h>
#include <hip/hip_bf16.h>

#define DIMK 3
#define NPTS 30
#define KK   181
#define PP   24360
#define DEMB 190
#define VLD  192   // padded vec row stride (floats)

#define SORT_N 32768

// ---------------------------------------------------------------------------
// Kernel 1: per-permutation inner embed -> vec (PP x VLD)
// One wave (64 lanes) per permutation p; 4 waves per block.
// Block recomputes G = matrix^T matrix (30x30) in LDS (cheap: 2700 FMA).
// Lane handles k = it*64 + lane, it in 0..2 (K=181).
// ---------------------------------------------------------------------------
__global__ __launch_bounds__(256) void k_inner(
    const float* __restrict__ M,      // 3 x 30
    const float* __restrict__ Ws_in,  // 181 x 3
    const float* __restrict__ Wd_in,  // 181 x 27
    float* __restrict__ vec)          // PP x VLD
{
    __shared__ float Gs[NPTS * NPTS];       // 900
    __shared__ float WsS[KK * 3];           // 543
    __shared__ float WdS[KK * 27];          // 4887

    const int tid = threadIdx.x;

    for (int i = tid; i < KK * 3; i += 256)  WsS[i] = Ws_in[i];
    for (int i = tid; i < KK * 27; i += 256) WdS[i] = Wd_in[i];
    for (int e = tid; e < NPTS * NPTS; e += 256) {
        int a = e / NPTS, b = e % NPTS;
        Gs[e] = M[a] * M[b] + M[NPTS + a] * M[NPTS + b] + M[2 * NPTS + a] * M[2 * NPTS + b];
    }
    __syncthreads();

    const int wave = tid >> 6;
    const int lane = tid & 63;
    const int p = blockIdx.x * 4 + wave;   // grid sized exactly: p < PP always

    // factorial-number-system decode of itertools.permutations(range(30),3)
    int i0 = p / 812;            // 812 = 29*28
    int r  = p - i0 * 812;
    int i1 = r / 28;
    int i2 = r - i1 * 28;
    int c0 = i0;
    int c1 = i1 + (i1 >= c0 ? 1 : 0);
    int lo = min(c0, c1), hi = max(c0, c1);
    int c2 = i2;
    if (c2 >= lo) c2++;
    if (c2 >= hi) c2++;

    float* vrow = vec + (long)p * VLD;

    // gram_flat: vec[p][3*i+j] = G[c_i, c_j]
    if (lane < 9) {
        int i = lane / 3, j = lane % 3;
        int ci = (i == 0) ? c0 : ((i == 1) ? c1 : c2);
        int cj = (j == 0) ? c0 : ((j == 1) ? c1 : c2);
        vrow[lane] = Gs[ci * NPTS + cj];
    }

    const float* g0 = Gs + c0 * NPTS;
    const float* g1 = Gs + c1 * NPTS;
    const float* g2 = Gs + c2 * NPTS;
    const float INF = __builtin_inff();

    for (int it = 0; it < 3; ++it) {
        int k = it * 64 + lane;
        if (k < KK) {
            float w0 = WsS[k * 3 + 0], w1 = WsS[k * 3 + 1], w2 = WsS[k * 3 + 2];
            float v[32];
#pragma unroll
            for (int j = 0; j < NPTS; ++j) {
                float val = w0 * g0[j] + w1 * g1[j] + w2 * g2[j];
                bool excl = (j == c0) | (j == c1) | (j == c2);
                v[j] = excl ? INF : val;
            }
            v[30] = INF;
            v[31] = INF;

            // fully-unrolled bitonic sort network over 32 registers (ascending)
#pragma unroll
            for (int sz = 2; sz <= 32; sz <<= 1) {
#pragma unroll
                for (int st = sz >> 1; st >= 1; st >>= 1) {
#pragma unroll
                    for (int i = 0; i < 32; ++i) {
                        int j = i ^ st;
                        if (j > i) {
                            bool up = ((i & sz) == 0);
                            float a = v[i], b = v[j];
                            float mn = fminf(a, b), mx = fmaxf(a, b);
                            v[i] = up ? mn : mx;
                            v[j] = up ? mx : mn;
                        }
                    }
                }
            }

            float emb = 0.f;
#pragma unroll
            for (int m = 0; m < 27; ++m) emb += WdS[k * 27 + m] * v[m];
            vrow[9 + k] = emb;
        } else if (k < 183) {
            vrow[9 + k] = 0.f;   // pad entries 190,191 of the 192-row
        }
    }
}

// ---------------------------------------------------------------------------
// Kernel 2: sm2T[k][p] = dot(vec[p][0:190], Ws_out[k][0:190])
// Tiled fp32 GEMM: 64 p x 64 k per block, D staged in two 96-chunks.
// LDS stride 97 -> conflict-free reads. 4x4 register micro-tile per thread.
// ---------------------------------------------------------------------------
#define BP  64
#define BK  64
#define DC  96
#define LDT 97

__global__ __launch_bounds__(256) void k_gemm(
    const float* __restrict__ vec,    // PP x VLD
    const float* __restrict__ Wout,   // 181 x 190
    float* __restrict__ sm2T)         // 181 x PP
{
    __shared__ float As[BP * LDT];
    __shared__ float Bs[BK * LDT];

    const int tid = threadIdx.x;
    const int pTile = blockIdx.x * BP;
    const int kTile = blockIdx.y * BK;
    const int tx = tid & 15;   // p direction
    const int ty = tid >> 4;   // k direction

    float acc[4][4];
#pragma unroll
    for (int i = 0; i < 4; ++i)
#pragma unroll
        for (int j = 0; j < 4; ++j) acc[i][j] = 0.f;

    for (int ch = 0; ch < 2; ++ch) {
        const int dbase = ch * DC;
        __syncthreads();
        for (int e = tid; e < BP * DC; e += 256) {
            int pl = e / DC, d = e - pl * DC;
            int pg = pTile + pl;
            As[pl * LDT + d] = (pg < PP) ? vec[(long)pg * VLD + dbase + d] : 0.f;
        }
        for (int e = tid; e < BK * DC; e += 256) {
            int kl = e / DC, d = e - kl * DC;
            int kg = kTile + kl;
            int dg = dbase + d;
            Bs[kl * LDT + d] = (kg < KK && dg < DEMB) ? Wout[kg * DEMB + dg] : 0.f;
        }
        __syncthreads();

        for (int d = 0; d < DC; ++d) {
            float a[4], b[4];
#pragma unroll
            for (int i = 0; i < 4; ++i) a[i] = As[(tx + 16 * i) * LDT + d];
#pragma unroll
            for (int j = 0; j < 4; ++j) b[j] = Bs[(ty + 16 * j) * LDT + d];
#pragma unroll
            for (int i = 0; i < 4; ++i)
#pragma unroll
                for (int j = 0; j < 4; ++j) acc[i][j] += a[i] * b[j];
        }
    }

#pragma unroll
    for (int j = 0; j < 4; ++j) {
        int kg = kTile + ty + 16 * j;
        if (kg < KK) {
#pragma unroll
            for (int i = 0; i < 4; ++i) {
                int pg = pTile + tx + 16 * i;
                if (pg < PP) sm2T[(long)kg * PP + pg] = acc[i][j];
            }
        }
    }
}

// ---------------------------------------------------------------------------
// Kernel 3: per-k full sort of the 24360-column (padded to 32768 with +inf)
// via LDS bitonic sort, then out[k] = sum_r Wd_out[k][r] * sorted[r].
// One block of 1024 threads per k; 128 KiB LDS (gfx950 has 160 KiB/WG).
// ---------------------------------------------------------------------------
__global__ __launch_bounds__(1024) void k_sort(
    const float* __restrict__ sm2T,   // 181 x PP
    const float* __restrict__ WdOut,  // 181 x PP
    float* __restrict__ out)          // 181
{
    __shared__ float s[SORT_N];
    const int k = blockIdx.x;
    const int tid = threadIdx.x;
    const float* col = sm2T + (long)k * PP;
    const float INF = __builtin_inff();

    for (int i = tid; i < SORT_N; i += 1024)
        s[i] = (i < PP) ? col[i] : INF;
    __syncthreads();

    for (int sz = 2; sz <= SORT_N; sz <<= 1) {
        for (int st = sz >> 1; st >= 1; st >>= 1) {
            const int mask = st - 1;
            for (int t = tid; t < SORT_N / 2; t += 1024) {
                int i = ((t & ~mask) << 1) | (t & mask);
                int j = i | st;
                bool up = ((i & sz) == 0);
                float a = s[i], b = s[j];
                float mn = fminf(a, b), mx = fmaxf(a, b);
                s[i] = up ? mn : mx;
                s[j] = up ? mx : mn;
            }
            __syncthreads();
        }
    }

    const float* wrow = WdOut + (long)k * PP;
    float local = 0.f;
    for (int r = tid; r < PP; r += 1024)
        local += wrow[r] * s[r];
    __syncthreads();

#pragma unroll
    for (int off = 32; off > 0; off >>= 1)
        local += __shfl_down(local, off, 64);
    if ((tid & 63) == 0) s[tid >> 6] = local;
    __syncthreads();
    if (tid < 16) {
        float x = s[tid];
#pragma unroll
        for (int off = 8; off > 0; off >>= 1)
            x += __shfl_down(x, off, 64);
        if (tid == 0) out[k] = x;
    }
}

// ---------------------------------------------------------------------------
extern "C" void kernel_launch(void* const* d_in, const int* in_sizes, int n_in,
                              void* d_out, int out_size, void* d_ws, size_t ws_size,
                              hipStream_t stream) {
    const float* M      = (const float*)d_in[0];
    const float* Ws_in  = (const float*)d_in[1];
    const float* Wd_in  = (const float*)d_in[2];
    const float* Ws_out = (const float*)d_in[3];
    const float* Wd_out = (const float*)d_in[4];
    float* out = (float*)d_out;

    float* vec  = (float*)d_ws;                    // PP*VLD floats = 18.7 MB
    float* sm2T = vec + (size_t)PP * VLD;          // KK*PP floats  = 17.6 MB

    k_inner<<<PP / 4, 256, 0, stream>>>(M, Ws_in, Wd_in, vec);

    dim3 g2((PP + BP - 1) / BP, (KK + BK - 1) / BK);
    k_gemm<<<g2, 256, 0, stream>>>(vec, Ws_out, sm2T);

    k_sort<<<KK, 1024, 0, stream>>>(sm2T, Wd_out, out);
}